// Round 9
// baseline (652.649 us; speedup 1.0000x reference)
//
#include <hip/hip_runtime.h>
#include <math.h>

#define N_NODES 50000
#define N_EDGES 800000
#define R_REL 8
#define H_DIM 128
#define C_OUT 64

typedef __attribute__((ext_vector_type(8))) __bf16 bf16x8;
typedef __attribute__((ext_vector_type(4))) __bf16 bf16x4;
typedef __attribute__((ext_vector_type(2))) __bf16 bf16x2;
typedef __attribute__((ext_vector_type(4))) float f32x4;

// ---------------- CSR build (dst-sorted edge list, packed (src<<3)|et) ----------------

__global__ void k_hist(const int* __restrict__ dst, int* __restrict__ hist) {
  int e = blockIdx.x * blockDim.x + threadIdx.x;
  if (e < N_EDGES) atomicAdd(&hist[dst[e]], 1);
}

__global__ __launch_bounds__(1024) void k_scan1(const int* __restrict__ hist,
                                                int* __restrict__ excl, int* __restrict__ bsum) {
  __shared__ int tmp[1024];
  int b = blockIdx.x, tid = threadIdx.x;
  int idx = b * 1024 + tid;
  int v = (idx < N_NODES) ? hist[idx] : 0;
  tmp[tid] = v;
  __syncthreads();
  for (int off = 1; off < 1024; off <<= 1) {
    int t = (tid >= off) ? tmp[tid - off] : 0;
    __syncthreads();
    tmp[tid] += t;
    __syncthreads();
  }
  if (idx < N_NODES) excl[idx] = tmp[tid] - v;
  if (tid == 1023) bsum[b] = tmp[1023];
}

__global__ void k_scan2(const int* __restrict__ bsum, int* __restrict__ boff) {
  if (threadIdx.x == 0) {
    int nb = (N_NODES + 1023) / 1024;
    int s = 0;
    for (int i = 0; i < nb; ++i) { boff[i] = s; s += bsum[i]; }
  }
}

__global__ void k_scan3(const int* __restrict__ excl, const int* __restrict__ boff,
                        int* __restrict__ rowptr, int* __restrict__ cursor) {
  int idx = blockIdx.x * blockDim.x + threadIdx.x;
  if (idx < N_NODES) {
    int v = excl[idx] + boff[idx >> 10];
    rowptr[idx] = v;
    cursor[idx] = v;
  }
  if (idx == 0) rowptr[N_NODES] = N_EDGES;
}

__global__ void k_scatter(const int* __restrict__ src, const int* __restrict__ dst,
                          const int* __restrict__ et, int* __restrict__ cursor,
                          int* __restrict__ spack) {
  int e = blockIdx.x * blockDim.x + threadIdx.x;
  if (e < N_EDGES) {
    int d = dst[e];
    int p = atomicAdd(&cursor[d], 1);
    spack[p] = (src[e] << 3) | et[e];
  }
}

// ---------------- x -> bf16 cast ----------------

__global__ void k_cast(const float* __restrict__ x, __bf16* __restrict__ xb) {
  int t = blockIdx.x * blockDim.x + threadIdx.x;
  if (t >= N_NODES * H_DIM / 8) return;
  const float4* xv = (const float4*)(x + (size_t)t * 8);
  float4 a = xv[0], b = xv[1];
  bf16x8 o;
  o[0] = (__bf16)a.x; o[1] = (__bf16)a.y; o[2] = (__bf16)a.z; o[3] = (__bf16)a.w;
  o[4] = (__bf16)b.x; o[5] = (__bf16)b.y; o[6] = (__bf16)b.z; o[7] = (__bf16)b.w;
  ((bf16x8*)xb)[t] = o;
}

// ---------------- W prep: concat-K (k = r*128+f), split-bf16, MFMA A-fragment order ----

__global__ void k_prepwfrag(const float* __restrict__ W1, const float* __restrict__ W2,
                            const float* __restrict__ W3,
                            __bf16* __restrict__ Fhi, __bf16* __restrict__ Flo) {
  int t = blockIdx.x * 256 + threadIdx.x;   // 3*32*8*64 = 49152
  if (t >= 49152) return;
  int lane = t & 63;
  int ot = (t >> 6) & 7;
  int kc = (t >> 9) & 31;
  int l  = t >> 14;
  int c = lane & 15, quad = lane >> 4;
  const float* W = (l == 0) ? W1 : (l == 1) ? W2 : W3;
  int k0 = kc * 32 + quad * 8;
  int r = k0 >> 7;
  int f0 = k0 & 127;
  int o = ot * 16 + c;
  const float* wp = W + ((size_t)r << 14) + (size_t)f0 * 128 + o;
  size_t ob = ((size_t)l * 131072) + (((size_t)kc * 8 + ot) * 64 + lane) * 8;
#pragma unroll
  for (int j = 0; j < 8; ++j) {
    float v = wp[j * 128];
    __bf16 h = (__bf16)v;
    Fhi[ob + j] = h;
    Flo[ob + j] = (__bf16)(v - (float)h);
  }
}

// ---------------- wq/wk prep: wq[l][r][f] = sum_o W[l][r][f][o] * q[l][o] ----------------

__global__ void k_prepwq(const float* __restrict__ W1, const float* __restrict__ W2,
                         const float* __restrict__ W3,
                         const float* __restrict__ q1, const float* __restrict__ k1,
                         const float* __restrict__ q2, const float* __restrict__ k2,
                         const float* __restrict__ q3, const float* __restrict__ k3,
                         float* __restrict__ wq, float* __restrict__ wk) {
  int idx = blockIdx.x * blockDim.x + threadIdx.x;  // [l][r][f], 3*8*128
  if (idx >= 3 * R_REL * 128) return;
  int r = (idx >> 7) & 7;
  int f = idx & 127;
  int l = idx >> 10;
  const float* W  = (l == 0) ? W1 : (l == 1) ? W2 : W3;
  const float* qv = (l == 0) ? q1 : (l == 1) ? q2 : q3;
  const float* kv = (l == 0) ? k1 : (l == 1) ? k2 : k3;
  const float4* row = (const float4*)(W + ((size_t)r << 14) + ((size_t)f << 7));
  const float4* q4 = (const float4*)qv;
  const float4* k4 = (const float4*)kv;
  float sq = 0.f, sk = 0.f;
#pragma unroll 8
  for (int i = 0; i < 32; ++i) {
    float4 w = row[i], qq = q4[i], kk = k4[i];
    sq += w.x * qq.x + w.y * qq.y + w.z * qq.z + w.w * qq.w;
    sk += w.x * kk.x + w.y * kk.y + w.z * kk.z + w.w * kk.w;
  }
  wq[idx] = sq;
  wk[idx] = sk;
}

// ---------------- pack wq/wk into MFMA A-fragments (split-bf16) ----------------

__global__ void k_prepqkfrag(const float* __restrict__ wq, const float* __restrict__ wk,
                             __bf16* __restrict__ Qhi, __bf16* __restrict__ Qlo) {
  int t = blockIdx.x * 256 + threadIdx.x;   // 3*4*64 = 768
  if (t >= 768) return;
  int lane = t & 63;
  int kb = (t >> 6) & 3;
  int l  = t >> 8;
  int c = lane & 15, quad = lane >> 4;
  const float* Mrow = (c < 8) ? (wq + l * 1024 + c * 128) : (wk + l * 1024 + (c - 8) * 128);
  size_t ob = ((size_t)(l * 4 + kb) * 64 + lane) * 8;
#pragma unroll
  for (int j = 0; j < 8; ++j) {
    float v = Mrow[kb * 32 + quad * 8 + j];
    __bf16 h = (__bf16)v;
    Qhi[ob + j] = h;
    Qlo[ob + j] = (__bf16)(v - (float)h);
  }
}

// ---------------- qx/kx via MFMA: D[m=(qk,r)][n=node] ----------------

__global__ __launch_bounds__(256) void k_qkx_mfma(
    const __bf16* __restrict__ xb,
    const __bf16* __restrict__ Qhi, const __bf16* __restrict__ Qlo,
    float* __restrict__ qx, float* __restrict__ kx)
{
  const int tid  = threadIdx.x;
  const int wave = tid >> 6;
  const int lane = tid & 63;
  const int quad = lane >> 4;
  const int c    = lane & 15;
  const int node = blockIdx.x * 64 + wave * 16 + c;
  const int ncl  = (node < N_NODES) ? node : (N_NODES - 1);

  f32x4 acc = (f32x4){0.f, 0.f, 0.f, 0.f};
#pragma unroll
  for (int kb = 0; kb < 4; ++kb) {
    bf16x8 B = *(const bf16x8*)(xb + (size_t)ncl * 128 + kb * 32 + quad * 8);
    bf16x8 ah = ((const bf16x8*)Qhi)[kb * 64 + lane];
    bf16x8 al = ((const bf16x8*)Qlo)[kb * 64 + lane];
    acc = __builtin_amdgcn_mfma_f32_16x16x32_bf16(ah, B, acc, 0, 0, 0);
    acc = __builtin_amdgcn_mfma_f32_16x16x32_bf16(al, B, acc, 0, 0, 0);
  }
  if (node < N_NODES) {
    float* base = (quad & 2) ? kx : qx;
    int off = (quad & 1) * 4;
    *(float4*)(base + (size_t)node * 8 + off) = make_float4(acc[0], acc[1], acc[2], acc[3]);
  }
}

// ---------------- phase A: per-dst online-softmax, bf16 feature aggregation ----------------
// block 512 = 8 waves = 8 nodes.  j-loop: batch-8 readlane -> 8 gathers in flight.

__global__ __launch_bounds__(512) void k_agg_feat(
    const __bf16* __restrict__ xb, const float* __restrict__ qx, const float* __restrict__ kx,
    const int* __restrict__ rowptr, const int* __restrict__ spack,
    __bf16* __restrict__ agg)
{
  const int nd = blockIdx.x * 8 + (threadIdx.x >> 6);
  const int lane = threadIdx.x & 63;
  if (nd >= N_NODES) return;
  const int s = rowptr[nd];
  const int deg = rowptr[nd + 1] - s;

  float m = -INFINITY, sum = 0.f;
  float2 acc[R_REL];
#pragma unroll
  for (int r = 0; r < R_REL; ++r) acc[r] = make_float2(0.f, 0.f);

  for (int c0 = 0; c0 < deg; c0 += 64) {
    int idx = c0 + lane;
    bool valid = idx < deg;
    int pk = valid ? spack[s + idx] : 0;
    float a = -INFINITY;
    if (valid) {
      float av = qx[(nd << 3) | (pk & 7)] + kx[pk];
      a = (av >= 0.f) ? av : 0.2f * av;   // leaky relu, slope 0.2
    }
    float cm = a;
#pragma unroll
    for (int off = 32; off > 0; off >>= 1) cm = fmaxf(cm, __shfl_xor(cm, off));
    float mnew = fmaxf(m, cm);
    float scale = (m == -INFINITY) ? 0.f : __expf(m - mnew);
    sum *= scale;
#pragma unroll
    for (int r = 0; r < R_REL; ++r) { acc[r].x *= scale; acc[r].y *= scale; }
    m = mnew;
    float ew = valid ? __expf(a - m) : 0.f;
    float cs = ew;
#pragma unroll
    for (int off = 32; off > 0; off >>= 1) cs += __shfl_xor(cs, off);
    sum += cs;
    int cnt = (deg - c0 < 64) ? (deg - c0) : 64;

#define ACC_EDGE(W_, V_, P_)                                                      \
    { float vx_ = (float)V_[0], vy_ = (float)V_[1];                               \
      switch (P_ & 7) {                                                           \
        case 0: acc[0].x += W_ * vx_; acc[0].y += W_ * vy_; break;                \
        case 1: acc[1].x += W_ * vx_; acc[1].y += W_ * vy_; break;                \
        case 2: acc[2].x += W_ * vx_; acc[2].y += W_ * vy_; break;                \
        case 3: acc[3].x += W_ * vx_; acc[3].y += W_ * vy_; break;                \
        case 4: acc[4].x += W_ * vx_; acc[4].y += W_ * vy_; break;                \
        case 5: acc[5].x += W_ * vx_; acc[5].y += W_ * vy_; break;                \
        case 6: acc[6].x += W_ * vx_; acc[6].y += W_ * vy_; break;                \
        default: acc[7].x += W_ * vx_; acc[7].y += W_ * vy_; break;               \
      } }

    int j = 0;
    for (; j + 8 <= cnt; j += 8) {
      int p[8];
      bf16x2 v[8];
#pragma unroll
      for (int u = 0; u < 8; ++u) p[u] = __builtin_amdgcn_readlane(pk, j + u);
#pragma unroll
      for (int u = 0; u < 8; ++u)
        v[u] = ((const bf16x2*)(xb + ((size_t)(p[u] >> 3) << 7)))[lane];
#pragma unroll
      for (int u = 0; u < 8; ++u) {
        float w = __uint_as_float(__builtin_amdgcn_readlane(__float_as_uint(ew), j + u));
        ACC_EDGE(w, v[u], p[u])
      }
    }
    for (; j < cnt; ++j) {
      int p0 = __builtin_amdgcn_readlane(pk, j);
      float w0 = __uint_as_float(__builtin_amdgcn_readlane(__float_as_uint(ew), j));
      bf16x2 v0 = ((const bf16x2*)(xb + ((size_t)(p0 >> 3) << 7)))[lane];
      ACC_EDGE(w0, v0, p0)
    }
#undef ACC_EDGE
  }
  float inv = (deg > 0) ? 1.f / sum : 0.f;
  bf16x2* ag2 = (bf16x2*)agg;
#pragma unroll
  for (int r = 0; r < R_REL; ++r) {
    bf16x2 o;
    o[0] = (__bf16)(acc[r].x * inv);
    o[1] = (__bf16)(acc[r].y * inv);
    ag2[((size_t)nd * R_REL + r) * 64 + lane] = o;
  }
}

// ---------------- phase B: h[n,:] (bf16) = relu( sum_k agg[n][k] * Wcat[k][:] + b ) ------

__global__ __launch_bounds__(512, 4) void k_gemm_out(
    const __bf16* __restrict__ agg,
    const __bf16* __restrict__ Fhi, const __bf16* __restrict__ Flo,
    const float* __restrict__ bias, __bf16* __restrict__ out)
{
  __shared__ bf16x8 sW[4096];            // [0,2048) hi, [2048,4096) lo — 64 KB
  const int tid  = threadIdx.x;
  const int wave = tid >> 6;
  const int lane = tid & 63;
  const int quad = lane >> 4;
  const int c    = lane & 15;

  const int node = blockIdx.x * 128 + wave * 16 + c;
  const int nclamp = (node < N_NODES) ? node : (N_NODES - 1);
  const bf16x8* Av = (const bf16x8*)(agg + (size_t)nclamp * 1024);

  f32x4 acc[8];
#pragma unroll
  for (int ot = 0; ot < 8; ++ot) acc[ot] = (f32x4){0.f, 0.f, 0.f, 0.f};

#pragma unroll 1
  for (int s = 0; s < 8; ++s) {          // K super-chunks of 128
    __syncthreads();
    {
      const float4* gh = (const float4*)(Fhi + (size_t)s * 16384);
      const float4* gl = (const float4*)(Flo + (size_t)s * 16384);
      float4* s4 = (float4*)sW;
#pragma unroll
      for (int i = 0; i < 4; ++i) {
        s4[tid + i * 512] = gh[tid + i * 512];
        s4[2048 + tid + i * 512] = gl[tid + i * 512];
      }
    }
    bf16x8 B[4];
#pragma unroll
    for (int kb = 0; kb < 4; ++kb) B[kb] = Av[s * 16 + kb * 4 + quad];
    __syncthreads();
#pragma unroll
    for (int kb = 0; kb < 4; ++kb) {
#pragma unroll
      for (int ot = 0; ot < 8; ++ot) {
        bf16x8 whi = sW[(kb * 8 + ot) * 64 + lane];
        bf16x8 wlo = sW[2048 + (kb * 8 + ot) * 64 + lane];
        acc[ot] = __builtin_amdgcn_mfma_f32_16x16x32_bf16(whi, B[kb], acc[ot], 0, 0, 0);
        acc[ot] = __builtin_amdgcn_mfma_f32_16x16x32_bf16(wlo, B[kb], acc[ot], 0, 0, 0);
      }
    }
  }

  if (node < N_NODES) {
    __bf16* dp = out + ((size_t)node << 7) + quad * 4;
#pragma unroll
    for (int ot = 0; ot < 8; ++ot) {
      float4 bb = *(const float4*)(bias + ot * 16 + quad * 4);
      bf16x4 o;
      o[0] = (__bf16)fmaxf(acc[ot][0] + bb.x, 0.f);
      o[1] = (__bf16)fmaxf(acc[ot][1] + bb.y, 0.f);
      o[2] = (__bf16)fmaxf(acc[ot][2] + bb.z, 0.f);
      o[3] = (__bf16)fmaxf(acc[ot][3] + bb.w, 0.f);
      *(bf16x4*)(dp + ot * 16) = o;
    }
  }
}

// ---------------- final linear + log_softmax (bf16 h) ----------------

__global__ __launch_bounds__(64) void k_final(
    const __bf16* __restrict__ h, const float* __restrict__ lw, const float* __restrict__ lb,
    float* __restrict__ out)
{
  const int nd = blockIdx.x;
  const int c = threadIdx.x;
  const bf16x8* hrow = (const bf16x8*)(h + (size_t)nd * 128);
  float acc = lb[c];
#pragma unroll 4
  for (int i = 0; i < 16; ++i) {
    bf16x8 a = hrow[i];
#pragma unroll
    for (int j = 0; j < 8; ++j) acc += (float)a[j] * lw[(i * 8 + j) * 64 + c];
  }
  float mx = acc;
#pragma unroll
  for (int off = 32; off > 0; off >>= 1) mx = fmaxf(mx, __shfl_xor(mx, off));
  float e = __expf(acc - mx);
  float ssum = e;
#pragma unroll
  for (int off = 32; off > 0; off >>= 1) ssum += __shfl_xor(ssum, off);
  out[(size_t)nd * 64 + c] = acc - mx - __logf(ssum);
}

// ---------------- launch ----------------

extern "C" void kernel_launch(void* const* d_in, const int* in_sizes, int n_in,
                              void* d_out, int out_size, void* d_ws, size_t ws_size,
                              hipStream_t stream) {
  const float* x   = (const float*)d_in[0];
  const int* ei    = (const int*)d_in[1];
  const int* etype = (const int*)d_in[2];
  const float* W1 = (const float*)d_in[3];
  const float* q1 = (const float*)d_in[4];
  const float* k1 = (const float*)d_in[5];
  const float* b1 = (const float*)d_in[6];
  const float* W2 = (const float*)d_in[7];
  const float* q2 = (const float*)d_in[8];
  const float* k2 = (const float*)d_in[9];
  const float* b2 = (const float*)d_in[10];
  const float* W3 = (const float*)d_in[11];
  const float* q3 = (const float*)d_in[12];
  const float* k3 = (const float*)d_in[13];
  const float* b3 = (const float*)d_in[14];
  const float* lw = (const float*)d_in[15];
  const float* lb = (const float*)d_in[16];
  float* outp = (float*)d_out;

  char* p = (char*)d_ws;
  auto alloc = [&](size_t bytes) {
    char* r = p;
    p += (bytes + 255) & ~(size_t)255;
    return r;
  };
  __bf16* agg = (__bf16*)alloc((size_t)N_NODES * R_REL * H_DIM * 2);  // 102.4 MB
  __bf16* xb  = (__bf16*)alloc((size_t)N_NODES * H_DIM * 2);          // 12.8 MB
  __bf16* hA  = (__bf16*)alloc((size_t)N_NODES * H_DIM * 2);
  __bf16* hB  = (__bf16*)alloc((size_t)N_NODES * H_DIM * 2);
  float* qx   = (float*)alloc((size_t)N_NODES * R_REL * 4);
  float* kx   = (float*)alloc((size_t)N_NODES * R_REL * 4);
  int* rowptr = (int*)alloc((size_t)(N_NODES + 1) * 4);
  int* cursor = (int*)alloc((size_t)N_NODES * 4);
  int* hist   = (int*)alloc((size_t)N_NODES * 4);
  int* excl   = (int*)alloc((size_t)N_NODES * 4);
  int* bsum   = (int*)alloc((size_t)64 * 4);
  int* boff   = (int*)alloc((size_t)64 * 4);
  int* spack  = (int*)alloc((size_t)N_EDGES * 4);
  __bf16* Fhi = (__bf16*)alloc((size_t)3 * 131072 * 2);   // 786 KB
  __bf16* Flo = (__bf16*)alloc((size_t)3 * 131072 * 2);
  float* wq   = (float*)alloc((size_t)3 * R_REL * 128 * 4);
  float* wk   = (float*)alloc((size_t)3 * R_REL * 128 * 4);
  __bf16* Qhi = (__bf16*)alloc((size_t)3 * 2048 * 2);
  __bf16* Qlo = (__bf16*)alloc((size_t)3 * 2048 * 2);

  const int* src = ei;            // edge_index[0]
  const int* dst = ei + N_EDGES;  // edge_index[1]

  const int nscan = (N_NODES + 1023) / 1024;

  // CSR build + W prep + x cast
  hipMemsetAsync(hist, 0, (size_t)N_NODES * 4, stream);
  k_hist<<<(N_EDGES + 255) / 256, 256, 0, stream>>>(dst, hist);
  k_cast<<<(N_NODES * H_DIM / 8 + 255) / 256, 256, 0, stream>>>(x, xb);
  k_prepwfrag<<<192, 256, 0, stream>>>(W1, W2, W3, Fhi, Flo);
  k_prepwq<<<(3 * R_REL * 128 + 255) / 256, 256, 0, stream>>>(W1, W2, W3, q1, k1, q2, k2, q3, k3, wq, wk);
  k_prepqkfrag<<<3, 256, 0, stream>>>(wq, wk, Qhi, Qlo);
  k_scan1<<<nscan, 1024, 0, stream>>>(hist, excl, bsum);
  k_scan2<<<1, 64, 0, stream>>>(bsum, boff);
  k_scan3<<<(N_NODES + 255) / 256, 256, 0, stream>>>(excl, boff, rowptr, cursor);
  k_scatter<<<(N_EDGES + 255) / 256, 256, 0, stream>>>(src, dst, etype, cursor, spack);

  const int qgrid = (N_NODES + 63) / 64;
  const int agrid = (N_NODES + 7) / 8;
  const int ggrid = (N_NODES + 127) / 128;
  const size_t WFL = 131072;
  const size_t QFL = 2048;

  // layer 1
  k_qkx_mfma<<<qgrid, 256, 0, stream>>>(xb, Qhi, Qlo, qx, kx);
  k_agg_feat<<<agrid, 512, 0, stream>>>(xb, qx, kx, rowptr, spack, agg);
  k_gemm_out<<<ggrid, 512, 0, stream>>>(agg, Fhi, Flo, b1, hA);
  // layer 2
  k_qkx_mfma<<<qgrid, 256, 0, stream>>>(hA, Qhi + QFL, Qlo + QFL, qx, kx);
  k_agg_feat<<<agrid, 512, 0, stream>>>(hA, qx, kx, rowptr, spack, agg);
  k_gemm_out<<<ggrid, 512, 0, stream>>>(agg, Fhi + WFL, Flo + WFL, b2, hB);
  // layer 3
  k_qkx_mfma<<<qgrid, 256, 0, stream>>>(hB, Qhi + 2 * QFL, Qlo + 2 * QFL, qx, kx);
  k_agg_feat<<<agrid, 512, 0, stream>>>(hB, qx, kx, rowptr, spack, agg);
  k_gemm_out<<<ggrid, 512, 0, stream>>>(agg, Fhi + 2 * WFL, Flo + 2 * WFL, b3, hA);
  // final linear + log_softmax
  k_final<<<N_NODES, 64, 0, stream>>>(hA, lw, lb, outp);
}

// Round 10
// 587.421 us; speedup vs baseline: 1.1110x; 1.1110x over previous
//
#include <hip/hip_runtime.h>
#include <math.h>

#define N_NODES 50000
#define N_EDGES 800000
#define R_REL 8
#define H_DIM 128
#define C_OUT 64

typedef __attribute__((ext_vector_type(8))) __bf16 bf16x8;
typedef __attribute__((ext_vector_type(4))) __bf16 bf16x4;
typedef __attribute__((ext_vector_type(2))) __bf16 bf16x2;
typedef __attribute__((ext_vector_type(4))) float f32x4;

// ---------------- CSR build (dst-sorted edge list, packed (src<<3)|et) ----------------

__global__ void k_hist(const int* __restrict__ dst, int* __restrict__ hist) {
  int e = blockIdx.x * blockDim.x + threadIdx.x;
  if (e < N_EDGES) atomicAdd(&hist[dst[e]], 1);
}

__global__ __launch_bounds__(1024) void k_scan1(const int* __restrict__ hist,
                                                int* __restrict__ excl, int* __restrict__ bsum) {
  __shared__ int tmp[1024];
  int b = blockIdx.x, tid = threadIdx.x;
  int idx = b * 1024 + tid;
  int v = (idx < N_NODES) ? hist[idx] : 0;
  tmp[tid] = v;
  __syncthreads();
  for (int off = 1; off < 1024; off <<= 1) {
    int t = (tid >= off) ? tmp[tid - off] : 0;
    __syncthreads();
    tmp[tid] += t;
    __syncthreads();
  }
  if (idx < N_NODES) excl[idx] = tmp[tid] - v;
  if (tid == 1023) bsum[b] = tmp[1023];
}

__global__ void k_scan2(const int* __restrict__ bsum, int* __restrict__ boff) {
  if (threadIdx.x == 0) {
    int nb = (N_NODES + 1023) / 1024;
    int s = 0;
    for (int i = 0; i < nb; ++i) { boff[i] = s; s += bsum[i]; }
  }
}

__global__ void k_scan3(const int* __restrict__ excl, const int* __restrict__ boff,
                        int* __restrict__ rowptr, int* __restrict__ cursor) {
  int idx = blockIdx.x * blockDim.x + threadIdx.x;
  if (idx < N_NODES) {
    int v = excl[idx] + boff[idx >> 10];
    rowptr[idx] = v;
    cursor[idx] = v;
  }
  if (idx == 0) rowptr[N_NODES] = N_EDGES;
}

__global__ void k_scatter(const int* __restrict__ src, const int* __restrict__ dst,
                          const int* __restrict__ et, int* __restrict__ cursor,
                          int* __restrict__ spack) {
  int e = blockIdx.x * blockDim.x + threadIdx.x;
  if (e < N_EDGES) {
    int d = dst[e];
    int p = atomicAdd(&cursor[d], 1);
    spack[p] = (src[e] << 3) | et[e];
  }
}

// ---------------- x -> bf16 cast ----------------

__global__ void k_cast(const float* __restrict__ x, __bf16* __restrict__ xb) {
  int t = blockIdx.x * blockDim.x + threadIdx.x;
  if (t >= N_NODES * H_DIM / 8) return;
  const float4* xv = (const float4*)(x + (size_t)t * 8);
  float4 a = xv[0], b = xv[1];
  bf16x8 o;
  o[0] = (__bf16)a.x; o[1] = (__bf16)a.y; o[2] = (__bf16)a.z; o[3] = (__bf16)a.w;
  o[4] = (__bf16)b.x; o[5] = (__bf16)b.y; o[6] = (__bf16)b.z; o[7] = (__bf16)b.w;
  ((bf16x8*)xb)[t] = o;
}

// ---------------- W prep: concat-K (k = r*128+f), split-bf16, MFMA A-fragment order ----

__global__ void k_prepwfrag(const float* __restrict__ W1, const float* __restrict__ W2,
                            const float* __restrict__ W3,
                            __bf16* __restrict__ Fhi, __bf16* __restrict__ Flo) {
  int t = blockIdx.x * 256 + threadIdx.x;   // 3*32*8*64 = 49152
  if (t >= 49152) return;
  int lane = t & 63;
  int ot = (t >> 6) & 7;
  int kc = (t >> 9) & 31;
  int l  = t >> 14;
  int c = lane & 15, quad = lane >> 4;
  const float* W = (l == 0) ? W1 : (l == 1) ? W2 : W3;
  int k0 = kc * 32 + quad * 8;
  int r = k0 >> 7;
  int f0 = k0 & 127;
  int o = ot * 16 + c;
  const float* wp = W + ((size_t)r << 14) + (size_t)f0 * 128 + o;
  size_t ob = ((size_t)l * 131072) + (((size_t)kc * 8 + ot) * 64 + lane) * 8;
#pragma unroll
  for (int j = 0; j < 8; ++j) {
    float v = wp[j * 128];
    __bf16 h = (__bf16)v;
    Fhi[ob + j] = h;
    Flo[ob + j] = (__bf16)(v - (float)h);
  }
}

// ---------------- wq/wk prep: wq[l][r][f] = sum_o W[l][r][f][o] * q[l][o] ----------------

__global__ void k_prepwq(const float* __restrict__ W1, const float* __restrict__ W2,
                         const float* __restrict__ W3,
                         const float* __restrict__ q1, const float* __restrict__ k1,
                         const float* __restrict__ q2, const float* __restrict__ k2,
                         const float* __restrict__ q3, const float* __restrict__ k3,
                         float* __restrict__ wq, float* __restrict__ wk) {
  int idx = blockIdx.x * blockDim.x + threadIdx.x;  // [l][r][f], 3*8*128
  if (idx >= 3 * R_REL * 128) return;
  int r = (idx >> 7) & 7;
  int f = idx & 127;
  int l = idx >> 10;
  const float* W  = (l == 0) ? W1 : (l == 1) ? W2 : W3;
  const float* qv = (l == 0) ? q1 : (l == 1) ? q2 : q3;
  const float* kv = (l == 0) ? k1 : (l == 1) ? k2 : k3;
  const float4* row = (const float4*)(W + ((size_t)r << 14) + ((size_t)f << 7));
  const float4* q4 = (const float4*)qv;
  const float4* k4 = (const float4*)kv;
  float sq = 0.f, sk = 0.f;
#pragma unroll 8
  for (int i = 0; i < 32; ++i) {
    float4 w = row[i], qq = q4[i], kk = k4[i];
    sq += w.x * qq.x + w.y * qq.y + w.z * qq.z + w.w * qq.w;
    sk += w.x * kk.x + w.y * kk.y + w.z * kk.z + w.w * kk.w;
  }
  wq[idx] = sq;
  wk[idx] = sk;
}

// ---------------- pack wq/wk into MFMA A-fragments (split-bf16) ----------------

__global__ void k_prepqkfrag(const float* __restrict__ wq, const float* __restrict__ wk,
                             __bf16* __restrict__ Qhi, __bf16* __restrict__ Qlo) {
  int t = blockIdx.x * 256 + threadIdx.x;   // 3*4*64 = 768
  if (t >= 768) return;
  int lane = t & 63;
  int kb = (t >> 6) & 3;
  int l  = t >> 8;
  int c = lane & 15, quad = lane >> 4;
  const float* Mrow = (c < 8) ? (wq + l * 1024 + c * 128) : (wk + l * 1024 + (c - 8) * 128);
  size_t ob = ((size_t)(l * 4 + kb) * 64 + lane) * 8;
#pragma unroll
  for (int j = 0; j < 8; ++j) {
    float v = Mrow[kb * 32 + quad * 8 + j];
    __bf16 h = (__bf16)v;
    Qhi[ob + j] = h;
    Qlo[ob + j] = (__bf16)(v - (float)h);
  }
}

// ---------------- qx/kx via MFMA: D[m=(qk,r)][n=node] ----------------

__global__ __launch_bounds__(256) void k_qkx_mfma(
    const __bf16* __restrict__ xb,
    const __bf16* __restrict__ Qhi, const __bf16* __restrict__ Qlo,
    float* __restrict__ qx, float* __restrict__ kx)
{
  const int tid  = threadIdx.x;
  const int wave = tid >> 6;
  const int lane = tid & 63;
  const int quad = lane >> 4;
  const int c    = lane & 15;
  const int node = blockIdx.x * 64 + wave * 16 + c;
  const int ncl  = (node < N_NODES) ? node : (N_NODES - 1);

  f32x4 acc = (f32x4){0.f, 0.f, 0.f, 0.f};
#pragma unroll
  for (int kb = 0; kb < 4; ++kb) {
    bf16x8 B = *(const bf16x8*)(xb + (size_t)ncl * 128 + kb * 32 + quad * 8);
    bf16x8 ah = ((const bf16x8*)Qhi)[kb * 64 + lane];
    bf16x8 al = ((const bf16x8*)Qlo)[kb * 64 + lane];
    acc = __builtin_amdgcn_mfma_f32_16x16x32_bf16(ah, B, acc, 0, 0, 0);
    acc = __builtin_amdgcn_mfma_f32_16x16x32_bf16(al, B, acc, 0, 0, 0);
  }
  if (node < N_NODES) {
    float* base = (quad & 2) ? kx : qx;
    int off = (quad & 1) * 4;
    *(float4*)(base + (size_t)node * 8 + off) = make_float4(acc[0], acc[1], acc[2], acc[3]);
  }
}

// ---------------- phase A: per-dst online-softmax, bf16 feature aggregation ----------------
// block 128 = 2 waves = 2 nodes (best measured occupancy).  j-loop: batch-16
// readlane -> 16 gathers in flight per wave.

__global__ __launch_bounds__(128) void k_agg_feat(
    const __bf16* __restrict__ xb, const float* __restrict__ qx, const float* __restrict__ kx,
    const int* __restrict__ rowptr, const int* __restrict__ spack,
    __bf16* __restrict__ agg)
{
  const int nd = blockIdx.x * 2 + (threadIdx.x >> 6);
  const int lane = threadIdx.x & 63;
  if (nd >= N_NODES) return;
  const int s = rowptr[nd];
  const int deg = rowptr[nd + 1] - s;

  float m = -INFINITY, sum = 0.f;
  float2 acc[R_REL];
#pragma unroll
  for (int r = 0; r < R_REL; ++r) acc[r] = make_float2(0.f, 0.f);

  for (int c0 = 0; c0 < deg; c0 += 64) {
    int idx = c0 + lane;
    bool valid = idx < deg;
    int pk = valid ? spack[s + idx] : 0;
    float a = -INFINITY;
    if (valid) {
      float av = qx[(nd << 3) | (pk & 7)] + kx[pk];
      a = (av >= 0.f) ? av : 0.2f * av;   // leaky relu, slope 0.2
    }
    float cm = a;
#pragma unroll
    for (int off = 32; off > 0; off >>= 1) cm = fmaxf(cm, __shfl_xor(cm, off));
    if (c0 == 0) {
      m = cm;                 // first chunk: no rescale needed
    } else {
      float mnew = fmaxf(m, cm);
      float scale = __expf(m - mnew);
      sum *= scale;
#pragma unroll
      for (int r = 0; r < R_REL; ++r) { acc[r].x *= scale; acc[r].y *= scale; }
      m = mnew;
    }
    float ew = valid ? __expf(a - m) : 0.f;
    float cs = ew;
#pragma unroll
    for (int off = 32; off > 0; off >>= 1) cs += __shfl_xor(cs, off);
    sum += cs;
    int cnt = (deg - c0 < 64) ? (deg - c0) : 64;

#define ACC_EDGE(W_, V_, P_)                                                      \
    { float vx_ = (float)V_[0], vy_ = (float)V_[1];                               \
      switch (P_ & 7) {                                                           \
        case 0: acc[0].x += W_ * vx_; acc[0].y += W_ * vy_; break;                \
        case 1: acc[1].x += W_ * vx_; acc[1].y += W_ * vy_; break;                \
        case 2: acc[2].x += W_ * vx_; acc[2].y += W_ * vy_; break;                \
        case 3: acc[3].x += W_ * vx_; acc[3].y += W_ * vy_; break;                \
        case 4: acc[4].x += W_ * vx_; acc[4].y += W_ * vy_; break;                \
        case 5: acc[5].x += W_ * vx_; acc[5].y += W_ * vy_; break;                \
        case 6: acc[6].x += W_ * vx_; acc[6].y += W_ * vy_; break;                \
        default: acc[7].x += W_ * vx_; acc[7].y += W_ * vy_; break;               \
      } }

    int j = 0;
    for (; j + 16 <= cnt; j += 16) {
      int p[16];
      bf16x2 v[16];
#pragma unroll
      for (int u = 0; u < 16; ++u) p[u] = __builtin_amdgcn_readlane(pk, j + u);
#pragma unroll
      for (int u = 0; u < 16; ++u)
        v[u] = ((const bf16x2*)(xb + ((size_t)(p[u] >> 3) << 7)))[lane];
#pragma unroll
      for (int u = 0; u < 16; ++u) {
        float w = __uint_as_float(__builtin_amdgcn_readlane(__float_as_uint(ew), j + u));
        ACC_EDGE(w, v[u], p[u])
      }
    }
    if (j + 8 <= cnt) {
      int p[8];
      bf16x2 v[8];
#pragma unroll
      for (int u = 0; u < 8; ++u) p[u] = __builtin_amdgcn_readlane(pk, j + u);
#pragma unroll
      for (int u = 0; u < 8; ++u)
        v[u] = ((const bf16x2*)(xb + ((size_t)(p[u] >> 3) << 7)))[lane];
#pragma unroll
      for (int u = 0; u < 8; ++u) {
        float w = __uint_as_float(__builtin_amdgcn_readlane(__float_as_uint(ew), j + u));
        ACC_EDGE(w, v[u], p[u])
      }
      j += 8;
    }
    for (; j < cnt; ++j) {
      int p0 = __builtin_amdgcn_readlane(pk, j);
      float w0 = __uint_as_float(__builtin_amdgcn_readlane(__float_as_uint(ew), j));
      bf16x2 v0 = ((const bf16x2*)(xb + ((size_t)(p0 >> 3) << 7)))[lane];
      ACC_EDGE(w0, v0, p0)
    }
#undef ACC_EDGE
  }
  float inv = (deg > 0) ? 1.f / sum : 0.f;
  bf16x2* ag2 = (bf16x2*)agg;
#pragma unroll
  for (int r = 0; r < R_REL; ++r) {
    bf16x2 o;
    o[0] = (__bf16)(acc[r].x * inv);
    o[1] = (__bf16)(acc[r].y * inv);
    ag2[((size_t)nd * R_REL + r) * 64 + lane] = o;
  }
}

// ---------------- phase B: h[n,:] (bf16) = relu( sum_k agg[n][k] * Wcat[k][:] + b ) ------

__global__ __launch_bounds__(512, 4) void k_gemm_out(
    const __bf16* __restrict__ agg,
    const __bf16* __restrict__ Fhi, const __bf16* __restrict__ Flo,
    const float* __restrict__ bias, __bf16* __restrict__ out)
{
  __shared__ bf16x8 sW[4096];            // [0,2048) hi, [2048,4096) lo — 64 KB
  const int tid  = threadIdx.x;
  const int wave = tid >> 6;
  const int lane = tid & 63;
  const int quad = lane >> 4;
  const int c    = lane & 15;

  const int node = blockIdx.x * 128 + wave * 16 + c;
  const int nclamp = (node < N_NODES) ? node : (N_NODES - 1);
  const bf16x8* Av = (const bf16x8*)(agg + (size_t)nclamp * 1024);

  f32x4 acc[8];
#pragma unroll
  for (int ot = 0; ot < 8; ++ot) acc[ot] = (f32x4){0.f, 0.f, 0.f, 0.f};

#pragma unroll 1
  for (int s = 0; s < 8; ++s) {          // K super-chunks of 128
    __syncthreads();
    {
      const float4* gh = (const float4*)(Fhi + (size_t)s * 16384);
      const float4* gl = (const float4*)(Flo + (size_t)s * 16384);
      float4* s4 = (float4*)sW;
#pragma unroll
      for (int i = 0; i < 4; ++i) {
        s4[tid + i * 512] = gh[tid + i * 512];
        s4[2048 + tid + i * 512] = gl[tid + i * 512];
      }
    }
    bf16x8 B[4];
#pragma unroll
    for (int kb = 0; kb < 4; ++kb) B[kb] = Av[s * 16 + kb * 4 + quad];
    __syncthreads();
#pragma unroll
    for (int kb = 0; kb < 4; ++kb) {
#pragma unroll
      for (int ot = 0; ot < 8; ++ot) {
        bf16x8 whi = sW[(kb * 8 + ot) * 64 + lane];
        bf16x8 wlo = sW[2048 + (kb * 8 + ot) * 64 + lane];
        acc[ot] = __builtin_amdgcn_mfma_f32_16x16x32_bf16(whi, B[kb], acc[ot], 0, 0, 0);
        acc[ot] = __builtin_amdgcn_mfma_f32_16x16x32_bf16(wlo, B[kb], acc[ot], 0, 0, 0);
      }
    }
  }

  if (node < N_NODES) {
    __bf16* dp = out + ((size_t)node << 7) + quad * 4;
#pragma unroll
    for (int ot = 0; ot < 8; ++ot) {
      float4 bb = *(const float4*)(bias + ot * 16 + quad * 4);
      bf16x4 o;
      o[0] = (__bf16)fmaxf(acc[ot][0] + bb.x, 0.f);
      o[1] = (__bf16)fmaxf(acc[ot][1] + bb.y, 0.f);
      o[2] = (__bf16)fmaxf(acc[ot][2] + bb.z, 0.f);
      o[3] = (__bf16)fmaxf(acc[ot][3] + bb.w, 0.f);
      *(bf16x4*)(dp + ot * 16) = o;
    }
  }
}

// ---------------- final linear + log_softmax (bf16 h) ----------------

__global__ __launch_bounds__(64) void k_final(
    const __bf16* __restrict__ h, const float* __restrict__ lw, const float* __restrict__ lb,
    float* __restrict__ out)
{
  const int nd = blockIdx.x;
  const int c = threadIdx.x;
  const bf16x8* hrow = (const bf16x8*)(h + (size_t)nd * 128);
  float acc = lb[c];
#pragma unroll 4
  for (int i = 0; i < 16; ++i) {
    bf16x8 a = hrow[i];
#pragma unroll
    for (int j = 0; j < 8; ++j) acc += (float)a[j] * lw[(i * 8 + j) * 64 + c];
  }
  float mx = acc;
#pragma unroll
  for (int off = 32; off > 0; off >>= 1) mx = fmaxf(mx, __shfl_xor(mx, off));
  float e = __expf(acc - mx);
  float ssum = e;
#pragma unroll
  for (int off = 32; off > 0; off >>= 1) ssum += __shfl_xor(ssum, off);
  out[(size_t)nd * 64 + c] = acc - mx - __logf(ssum);
}

// ---------------- launch ----------------

extern "C" void kernel_launch(void* const* d_in, const int* in_sizes, int n_in,
                              void* d_out, int out_size, void* d_ws, size_t ws_size,
                              hipStream_t stream) {
  const float* x   = (const float*)d_in[0];
  const int* ei    = (const int*)d_in[1];
  const int* etype = (const int*)d_in[2];
  const float* W1 = (const float*)d_in[3];
  const float* q1 = (const float*)d_in[4];
  const float* k1 = (const float*)d_in[5];
  const float* b1 = (const float*)d_in[6];
  const float* W2 = (const float*)d_in[7];
  const float* q2 = (const float*)d_in[8];
  const float* k2 = (const float*)d_in[9];
  const float* b2 = (const float*)d_in[10];
  const float* W3 = (const float*)d_in[11];
  const float* q3 = (const float*)d_in[12];
  const float* k3 = (const float*)d_in[13];
  const float* b3 = (const float*)d_in[14];
  const float* lw = (const float*)d_in[15];
  const float* lb = (const float*)d_in[16];
  float* outp = (float*)d_out;

  char* p = (char*)d_ws;
  auto alloc = [&](size_t bytes) {
    char* r = p;
    p += (bytes + 255) & ~(size_t)255;
    return r;
  };
  __bf16* agg = (__bf16*)alloc((size_t)N_NODES * R_REL * H_DIM * 2);  // 102.4 MB
  __bf16* xb  = (__bf16*)alloc((size_t)N_NODES * H_DIM * 2);          // 12.8 MB
  __bf16* hA  = (__bf16*)alloc((size_t)N_NODES * H_DIM * 2);
  __bf16* hB  = (__bf16*)alloc((size_t)N_NODES * H_DIM * 2);
  float* qx   = (float*)alloc((size_t)N_NODES * R_REL * 4);
  float* kx   = (float*)alloc((size_t)N_NODES * R_REL * 4);
  int* rowptr = (int*)alloc((size_t)(N_NODES + 1) * 4);
  int* cursor = (int*)alloc((size_t)N_NODES * 4);
  int* hist   = (int*)alloc((size_t)N_NODES * 4);
  int* excl   = (int*)alloc((size_t)N_NODES * 4);
  int* bsum   = (int*)alloc((size_t)64 * 4);
  int* boff   = (int*)alloc((size_t)64 * 4);
  int* spack  = (int*)alloc((size_t)N_EDGES * 4);
  __bf16* Fhi = (__bf16*)alloc((size_t)3 * 131072 * 2);   // 786 KB
  __bf16* Flo = (__bf16*)alloc((size_t)3 * 131072 * 2);
  float* wq   = (float*)alloc((size_t)3 * R_REL * 128 * 4);
  float* wk   = (float*)alloc((size_t)3 * R_REL * 128 * 4);
  __bf16* Qhi = (__bf16*)alloc((size_t)3 * 2048 * 2);
  __bf16* Qlo = (__bf16*)alloc((size_t)3 * 2048 * 2);

  const int* src = ei;            // edge_index[0]
  const int* dst = ei + N_EDGES;  // edge_index[1]

  const int nscan = (N_NODES + 1023) / 1024;

  // CSR build + W prep + x cast
  hipMemsetAsync(hist, 0, (size_t)N_NODES * 4, stream);
  k_hist<<<(N_EDGES + 255) / 256, 256, 0, stream>>>(dst, hist);
  k_cast<<<(N_NODES * H_DIM / 8 + 255) / 256, 256, 0, stream>>>(x, xb);
  k_prepwfrag<<<192, 256, 0, stream>>>(W1, W2, W3, Fhi, Flo);
  k_prepwq<<<(3 * R_REL * 128 + 255) / 256, 256, 0, stream>>>(W1, W2, W3, q1, k1, q2, k2, q3, k3, wq, wk);
  k_prepqkfrag<<<3, 256, 0, stream>>>(wq, wk, Qhi, Qlo);
  k_scan1<<<nscan, 1024, 0, stream>>>(hist, excl, bsum);
  k_scan2<<<1, 64, 0, stream>>>(bsum, boff);
  k_scan3<<<(N_NODES + 255) / 256, 256, 0, stream>>>(excl, boff, rowptr, cursor);
  k_scatter<<<(N_EDGES + 255) / 256, 256, 0, stream>>>(src, dst, etype, cursor, spack);

  const int qgrid = (N_NODES + 63) / 64;
  const int agrid = (N_NODES + 1) / 2;
  const int ggrid = (N_NODES + 127) / 128;
  const size_t WFL = 131072;
  const size_t QFL = 2048;

  // layer 1
  k_qkx_mfma<<<qgrid, 256, 0, stream>>>(xb, Qhi, Qlo, qx, kx);
  k_agg_feat<<<agrid, 128, 0, stream>>>(xb, qx, kx, rowptr, spack, agg);
  k_gemm_out<<<ggrid, 512, 0, stream>>>(agg, Fhi, Flo, b1, hA);
  // layer 2
  k_qkx_mfma<<<qgrid, 256, 0, stream>>>(hA, Qhi + QFL, Qlo + QFL, qx, kx);
  k_agg_feat<<<agrid, 128, 0, stream>>>(hA, qx, kx, rowptr, spack, agg);
  k_gemm_out<<<ggrid, 512, 0, stream>>>(agg, Fhi + WFL, Flo + WFL, b2, hB);
  // layer 3
  k_qkx_mfma<<<qgrid, 256, 0, stream>>>(hB, Qhi + 2 * QFL, Qlo + 2 * QFL, qx, kx);
  k_agg_feat<<<agrid, 128, 0, stream>>>(hB, qx, kx, rowptr, spack, agg);
  k_gemm_out<<<ggrid, 512, 0, stream>>>(agg, Fhi + 2 * WFL, Flo + 2 * WFL, b3, hA);
  // final linear + log_softmax
  k_final<<<N_NODES, 64, 0, stream>>>(hA, lw, lb, outp);
}